// Round 4
// baseline (274.878 us; speedup 1.0000x reference)
//
#include <hip/hip_runtime.h>

#define DI __device__ __forceinline__

typedef __bf16 bf8 __attribute__((ext_vector_type(8)));
typedef float f4 __attribute__((ext_vector_type(4)));
typedef unsigned short us4 __attribute__((ext_vector_type(4)));

// dims
#define BB 8
#define NN 4096
#define DD 512
#define RED 128
#define GG 32
#define HID 129

DI float b2f(unsigned short u) {
    union { unsigned int i; float f; } c; c.i = ((unsigned int)u) << 16; return c.f;
}
DI unsigned short f2b(float f) {
    union { float f; unsigned int i; } c; c.f = f;
    unsigned int u = c.i;
    return (unsigned short)((u + 0x7fffu + ((u >> 16) & 1u)) >> 16);
}

// ---------------- kernel 0: convert conv1_w (128x512) + conv2_w (32x128) to bf16 ----------------
__global__ __launch_bounds__(256) void kcvt(const float* __restrict__ conv1_w,
                                            const float* __restrict__ conv2_w,
                                            unsigned short* __restrict__ c1b,
                                            unsigned short* __restrict__ c2b) {
    int i = blockIdx.x * 256 + threadIdx.x;   // chunk id, 4 elements each
    const float* src;
    unsigned short* dst;
    size_t off;
    if (i < 16384) { src = conv1_w; dst = c1b; off = (size_t)i * 4; }
    else           { src = conv2_w; dst = c2b; off = (size_t)(i - 16384) * 4; }
    float4 v = *(const float4*)(src + off);
    us4 o;
    o[0] = f2b(v.x); o[1] = f2b(v.y); o[2] = f2b(v.z); o[3] = f2b(v.w);
    *(us4*)(dst + off) = o;
}

// ---------------- kernel 1: partial pooled sums over N + x -> bf16 conversion ----------------
// grid (64, 8), 256 threads. 64 rows per block, float4 per lane.
__global__ __launch_bounds__(256) void kpool(const float* __restrict__ x,
                                             float* __restrict__ part,
                                             unsigned short* __restrict__ xb) {
    int c = blockIdx.x, b = blockIdx.y, t = threadIdx.x;
    int rg = t >> 7, cg = t & 127;
    int row0 = c * 64;
    float4 s = {0.f, 0.f, 0.f, 0.f};
#pragma unroll 8
    for (int i = rg; i < 64; i += 2) {
        size_t off = ((size_t)(b * NN + row0 + i) * DD) + cg * 4;
        float4 v = *(const float4*)(x + off);
        s.x += v.x; s.y += v.y; s.z += v.z; s.w += v.w;
        us4 o;
        o[0] = f2b(v.x); o[1] = f2b(v.y); o[2] = f2b(v.z); o[3] = f2b(v.w);
        *(us4*)(xb + off) = o;
    }
    float* pp = part + ((size_t)((b * 64 + c) * 2 + rg) * DD) + cg * 4;
    pp[0] = s.x; pp[1] = s.y; pp[2] = s.z; pp[3] = s.w;
}

// ---------------- kernel 2a: attention MLP + softmax + bb ----------------
// grid 8 (one per b), 256 threads
__global__ __launch_bounds__(256) void katt(const float* __restrict__ part,
                                            const float* __restrict__ fc1_w,
                                            const float* __restrict__ fc2_w,
                                            const float* __restrict__ fc2_b,
                                            const float* __restrict__ dyn_b,
                                            float* __restrict__ att, float* __restrict__ bb) {
    int b = blockIdx.x, t = threadIdx.x;
    __shared__ float pooled[DD];
    __shared__ float a_s[HID + 3];
    __shared__ float att_s[4];
    for (int d = t; d < DD; d += 256) {
        float s = 0.f;
        for (int cc = 0; cc < 128; ++cc) s += part[(size_t)(b * 128 + cc) * DD + d];
        pooled[d] = s * (1.0f / (float)NN);
    }
    __syncthreads();
    int wv = t >> 6, ln = t & 63;
    for (int j = wv; j < HID; j += 4) {
        const float* wr = fc1_w + (size_t)j * DD + ln * 8;
        float4 w0 = *(const float4*)wr;
        float4 w1 = *(const float4*)(wr + 4);
        const float* pl = pooled + ln * 8;
        float s = w0.x * pl[0] + w0.y * pl[1] + w0.z * pl[2] + w0.w * pl[3] +
                  w1.x * pl[4] + w1.y * pl[5] + w1.z * pl[6] + w1.w * pl[7];
#pragma unroll
        for (int off = 32; off >= 1; off >>= 1) s += __shfl_xor(s, off);
        if (ln == 0) a_s[j] = fmaxf(s, 0.f);
    }
    __syncthreads();
    if (t == 0) {
        float lg[4], mx = -1e30f;
        for (int k = 0; k < 4; ++k) {
            float s = fc2_b[k];
            for (int j = 0; j < HID; ++j) s += a_s[j] * fc2_w[k * HID + j];
            lg[k] = s * (1.0f / 34.0f);
            mx = fmaxf(mx, lg[k]);
        }
        float den = 0.f;
        for (int k = 0; k < 4; ++k) { lg[k] = __expf(lg[k] - mx); den += lg[k]; }
        for (int k = 0; k < 4; ++k) {
            float a = lg[k] / den;
            att_s[k] = a; att[b * 4 + k] = a;
        }
    }
    __syncthreads();
    float a0 = att_s[0], a1 = att_s[1], a2 = att_s[2], a3 = att_s[3];
    for (int o = t; o < DD; o += 256) {
        bb[b * DD + o] = a0 * dyn_b[o] + a1 * dyn_b[DD + o] +
                         a2 * dyn_b[2 * DD + o] + a3 * dyn_b[3 * DD + o];
    }
}

// ---------------- kernel 2b: Wb[b,o,d] = sum_k att[b,k]*dyn_w[k,o,d]  (fp32 in, bf16 out) ----------------
__global__ __launch_bounds__(256) void kwb(const float* __restrict__ dyn_w,
                                           const float* __restrict__ att,
                                           unsigned short* __restrict__ Wb) {
    int g = blockIdx.x * 256 + threadIdx.x;     // 0..65535
    size_t pos = (size_t)g * 4;                 // within 512*512
    float4 w0 = *(const float4*)(dyn_w + pos);
    float4 w1 = *(const float4*)(dyn_w + 262144 + pos);
    float4 w2 = *(const float4*)(dyn_w + 524288 + pos);
    float4 w3 = *(const float4*)(dyn_w + 786432 + pos);
#pragma unroll
    for (int b = 0; b < 8; ++b) {
        float a0 = att[b * 4 + 0], a1 = att[b * 4 + 1], a2 = att[b * 4 + 2], a3 = att[b * 4 + 3];
        us4 o;
        o[0] = f2b(a0 * w0.x + a1 * w1.x + a2 * w2.x + a3 * w3.x);
        o[1] = f2b(a0 * w0.y + a1 * w1.y + a2 * w2.y + a3 * w3.y);
        o[2] = f2b(a0 * w0.z + a1 * w1.z + a2 * w2.z + a3 * w3.z);
        o[3] = f2b(a0 * w0.w + a1 * w1.w + a2 * w2.w + a3 * w3.w);
        *(us4*)(Wb + (size_t)b * 262144 + pos) = o;
    }
}

// ---------------- kernel 3: fused involution + dynconv + LN + residual ----------------
// grid 512 (b = bid&7 for XCD locality), 512 threads (8 waves), M=64 rows/block
// (512,2): 256-reg budget. K-loop uses register ping-pong prefetch: loads for
// iteration ks+1 issue before the MFMAs of iteration ks -> latency hidden.
__global__ __launch_bounds__(512, 2) void kmain(
    const unsigned short* __restrict__ xb, const unsigned short* __restrict__ c1b,
    const float* __restrict__ bn_g, const float* __restrict__ bn_b,
    const float* __restrict__ bn_m, const float* __restrict__ bn_v,
    const unsigned short* __restrict__ c2b, const float* __restrict__ conv2_b,
    const unsigned short* __restrict__ Wb, const float* __restrict__ bb,
    const float* __restrict__ lnG, const float* __restrict__ lnB,
    float* __restrict__ out) {
    int bid = blockIdx.x;
    int b = bid & 7, tile = bid >> 3;
    int row0 = tile * 64;
    int t = threadIdx.x;
    int w = t >> 6, lane = t & 63, q = lane >> 4, l16 = lane & 15;

    __shared__ float bnS[RED], bnT[RED];
    __shared__ float lnGs[DD], lnBs[DD];
    __shared__ unsigned short h_s[64][136];
    __shared__ float gate_s[64][32];
    __shared__ float redS[64][8], redQ[64][8];
    __shared__ float mu_s[64], rs_s[64];

    if (t < RED) {
        float sc = bn_g[t] * rsqrtf(bn_v[t] + 1e-5f);
        bnS[t] = sc;
        bnT[t] = bn_b[t] - bn_m[t] * sc;
    }
    lnGs[t] = lnG[t];
    lnBs[t] = lnB[t];

    // ---- K loop: out2 (N=512) + h (N=128) GEMMs, B^T-layout fragments ----
    f4 acc[4][4];
    f4 hacc[4];
#pragma unroll
    for (int mi = 0; mi < 4; ++mi) {
        hacc[mi] = (f4){0.f, 0.f, 0.f, 0.f};
#pragma unroll
        for (int ni = 0; ni < 4; ++ni) acc[mi][ni] = (f4){0.f, 0.f, 0.f, 0.f};
    }
    const int c0 = w * 64;
    const unsigned short* xp = xb + ((size_t)(b * NN + row0 + l16) * DD) + q * 8;
    const unsigned short* wp = Wb + ((size_t)(b * DD + c0 + l16) * DD) + q * 8;
    const unsigned short* cp = c1b + ((size_t)(w * 16 + l16) * DD) + q * 8;

    // preload ks=0 fragments
    bf8 afc[4], wbc[4], hbc;
#pragma unroll
    for (int mi = 0; mi < 4; ++mi) afc[mi] = *(const bf8*)(xp + mi * 16 * DD);
#pragma unroll
    for (int ni = 0; ni < 4; ++ni) wbc[ni] = *(const bf8*)(wp + ni * 16 * DD);
    hbc = *(const bf8*)cp;

#pragma unroll
    for (int ks = 0; ks < 16; ++ks) {
        const int kn = (ks < 15 ? ks + 1 : 15) * 32;
        bf8 afn[4], wbn[4], hbn;
#pragma unroll
        for (int mi = 0; mi < 4; ++mi) afn[mi] = *(const bf8*)(xp + mi * 16 * DD + kn);
        hbn = *(const bf8*)(cp + kn);
#pragma unroll
        for (int ni = 0; ni < 4; ++ni) wbn[ni] = *(const bf8*)(wp + ni * 16 * DD + kn);
        // MFMAs on current fragments (no wait needed: operands already resident)
#pragma unroll
        for (int mi = 0; mi < 4; ++mi)
            hacc[mi] = __builtin_amdgcn_mfma_f32_16x16x32_bf16(afc[mi], hbc, hacc[mi], 0, 0, 0);
#pragma unroll
        for (int ni = 0; ni < 4; ++ni) {
#pragma unroll
            for (int mi = 0; mi < 4; ++mi)
                acc[mi][ni] = __builtin_amdgcn_mfma_f32_16x16x32_bf16(afc[mi], wbc[ni], acc[mi][ni], 0, 0, 0);
        }
#pragma unroll
        for (int mi = 0; mi < 4; ++mi) afc[mi] = afn[mi];
#pragma unroll
        for (int ni = 0; ni < 4; ++ni) wbc[ni] = wbn[ni];
        hbc = hbn;
    }
    __syncthreads();   // covers bnS/lnGs init too

    // ---- h: BN + ReLU -> bf16 -> LDS ----
    {
        int hc = w * 16 + l16;
        float sc = bnS[hc], sh = bnT[hc];
#pragma unroll
        for (int mi = 0; mi < 4; ++mi) {
#pragma unroll
            for (int r = 0; r < 4; ++r) {
                int row = mi * 16 + q * 4 + r;
                float v = fmaxf(hacc[mi][r] * sc + sh, 0.f);
                h_s[row][hc] = f2b(v);
            }
        }
    }
    __syncthreads();

    // ---- gate = h @ conv2_w^T + conv2_b  (MFMA, K=128) ----
    {
        int mi_g = w >> 1, gi = w & 1;
        f4 g4 = (f4){0.f, 0.f, 0.f, 0.f};
#pragma unroll
        for (int ks = 0; ks < 4; ++ks) {
            bf8 ah = *(const bf8*)(&h_s[mi_g * 16 + l16][ks * 32 + q * 8]);
            bf8 bh = *(const bf8*)(c2b + (gi * 16 + l16) * RED + ks * 32 + q * 8);
            g4 = __builtin_amdgcn_mfma_f32_16x16x32_bf16(ah, bh, g4, 0, 0, 0);
        }
        float cb = conv2_b[gi * 16 + l16];
#pragma unroll
        for (int r = 0; r < 4; ++r)
            gate_s[mi_g * 16 + q * 4 + r][gi * 16 + l16] = g4[r] + cb;
    }
    __syncthreads();

    // ---- y = out2 + bb + x*gate ; LN stats ----
    float sum[4][4], sq[4][4];
#pragma unroll
    for (int mi = 0; mi < 4; ++mi)
#pragma unroll
        for (int r = 0; r < 4; ++r) { sum[mi][r] = 0.f; sq[mi][r] = 0.f; }

    const float* bbp = bb + b * DD;
#pragma unroll
    for (int mi = 0; mi < 4; ++mi) {
#pragma unroll
        for (int ni = 0; ni < 4; ++ni) {
            int col = c0 + ni * 16 + l16;
            float bbv = bbp[col];
            int gidx = (c0 >> 4) + ni;
#pragma unroll
            for (int r = 0; r < 4; ++r) {
                int row = mi * 16 + q * 4 + r;
                float xv = b2f(xb[((size_t)(b * NN + row0 + row) * DD) + col]);
                float y = acc[mi][ni][r] + bbv + xv * gate_s[row][gidx];
                acc[mi][ni][r] = y;
                sum[mi][r] += y;
                sq[mi][r] += y * y;
            }
        }
    }
    // reduce over the 16-lane column group
#pragma unroll
    for (int mi = 0; mi < 4; ++mi) {
#pragma unroll
        for (int r = 0; r < 4; ++r) {
            float s = sum[mi][r], qq = sq[mi][r];
#pragma unroll
            for (int off = 1; off < 16; off <<= 1) {
                s += __shfl_xor(s, off);
                qq += __shfl_xor(qq, off);
            }
            sum[mi][r] = s; sq[mi][r] = qq;
        }
    }
    if (l16 == 0) {
#pragma unroll
        for (int mi = 0; mi < 4; ++mi)
#pragma unroll
            for (int r = 0; r < 4; ++r) {
                int row = mi * 16 + q * 4 + r;
                redS[row][w] = sum[mi][r];
                redQ[row][w] = sq[mi][r];
            }
    }
    __syncthreads();
    if (t < 64) {
        float S = 0.f, Q = 0.f;
#pragma unroll
        for (int j = 0; j < 8; ++j) { S += redS[t][j]; Q += redQ[t][j]; }
        float mu = S * (1.f / 512.f);
        float var = Q * (1.f / 512.f) - mu * mu;
        mu_s[t] = mu;
        rs_s[t] = rsqrtf(var + 1e-5f);
    }
    __syncthreads();

    // ---- normalize, +x residual, store (fp32) ----
#pragma unroll
    for (int mi = 0; mi < 4; ++mi) {
#pragma unroll
        for (int ni = 0; ni < 4; ++ni) {
            int col = c0 + ni * 16 + l16;
            float lg = lnGs[col], lb = lnBs[col];
#pragma unroll
            for (int r = 0; r < 4; ++r) {
                int row = mi * 16 + q * 4 + r;
                size_t idx = ((size_t)(b * NN + row0 + row) * DD) + col;
                float xv = b2f(xb[idx]);
                float o = (acc[mi][ni][r] - mu_s[row]) * rs_s[row] * lg + lb + xv;
                out[idx] = o;
            }
        }
    }
}

extern "C" void kernel_launch(void* const* d_in, const int* in_sizes, int n_in,
                              void* d_out, int out_size, void* d_ws, size_t ws_size,
                              hipStream_t stream) {
    const float* x       = (const float*)d_in[0];
    const float* conv1_w = (const float*)d_in[1];
    const float* bn_g    = (const float*)d_in[2];
    const float* bn_b    = (const float*)d_in[3];
    const float* bn_m    = (const float*)d_in[4];
    const float* bn_v    = (const float*)d_in[5];
    const float* conv2_w = (const float*)d_in[6];
    const float* conv2_b = (const float*)d_in[7];
    const float* fc1_w   = (const float*)d_in[8];
    const float* fc2_w   = (const float*)d_in[9];
    const float* fc2_b   = (const float*)d_in[10];
    const float* dyn_w   = (const float*)d_in[11];
    const float* dyn_b   = (const float*)d_in[12];
    const float* lnG     = (const float*)d_in[13];
    const float* lnB     = (const float*)d_in[14];
    float* out = (float*)d_out;

    char* ws = (char*)d_ws;
    unsigned short* xb   = (unsigned short*)ws;                // 33554432 B
    float* part          = (float*)(ws + 33554432);            // 2097152 B
    float* att           = (float*)(ws + 35651584);            // 128 B
    float* bbw           = (float*)(ws + 35651712);            // 16384 B
    unsigned short* c1b  = (unsigned short*)(ws + 35668096);   // 131072 B
    unsigned short* c2b  = (unsigned short*)(ws + 35799168);   // 8192 B
    unsigned short* Wb   = (unsigned short*)(ws + 35807360);   // 4194304 B (total ~40 MB)

    kcvt<<<68, 256, 0, stream>>>(conv1_w, conv2_w, c1b, c2b);
    kpool<<<dim3(64, 8), 256, 0, stream>>>(x, part, xb);
    katt<<<8, 256, 0, stream>>>(part, fc1_w, fc2_w, fc2_b, dyn_b, att, bbw);
    kwb<<<256, 256, 0, stream>>>(dyn_w, att, Wb);
    kmain<<<512, 512, 0, stream>>>(xb, c1b, bn_g, bn_b, bn_m, bn_v, c2b, conv2_b,
                                   Wb, bbw, lnG, lnB, out);
}

// Round 5
// 255.274 us; speedup vs baseline: 1.0768x; 1.0768x over previous
//
#include <hip/hip_runtime.h>

#define DI __device__ __forceinline__

typedef __bf16 bf8 __attribute__((ext_vector_type(8)));
typedef float f4 __attribute__((ext_vector_type(4)));
typedef unsigned short us4 __attribute__((ext_vector_type(4)));
typedef unsigned short us8 __attribute__((ext_vector_type(8)));

// dims
#define BB 8
#define NN 4096
#define DD 512
#define RED 128
#define GG 32
#define HID 129

DI float b2f(unsigned short u) {
    union { unsigned int i; float f; } c; c.i = ((unsigned int)u) << 16; return c.f;
}
DI unsigned short f2b(float f) {
    union { float f; unsigned int i; } c; c.f = f;
    unsigned int u = c.i;
    return (unsigned short)((u + 0x7fffu + ((u >> 16) & 1u)) >> 16);
}

typedef const __attribute__((address_space(1))) void* gp1_t;
typedef __attribute__((address_space(3))) void* lp3_t;
// async global->LDS DMA, 16B per lane; lds base must be wave-uniform, HW adds lane*16
DI void gld16(const void* g, void* l) {
    __builtin_amdgcn_global_load_lds((gp1_t)g, (lp3_t)l, 16, 0, 0);
}

// ---------------- kernel 1: x -> bf16 + pooled partial sums, with kcvt merged ----------------
// grid (137, 8): blockIdx.x < 128 -> pool (32 rows each); else weight-convert blocks
__global__ __launch_bounds__(256) void kpre(const float* __restrict__ x,
                                            const float* __restrict__ conv1_w,
                                            const float* __restrict__ conv2_w,
                                            float* __restrict__ part,
                                            unsigned short* __restrict__ xb,
                                            unsigned short* __restrict__ c1b,
                                            unsigned short* __restrict__ c2b) {
    int c = blockIdx.x, b = blockIdx.y, t = threadIdx.x;
    if (c >= 128) {
        int idx = ((c - 128) * 8 + b) * 256 + t;    // 0..18431, need 17408
        if (idx < 16384) {
            size_t off = (size_t)idx * 4;
            float4 v = *(const float4*)(conv1_w + off);
            us4 o; o[0] = f2b(v.x); o[1] = f2b(v.y); o[2] = f2b(v.z); o[3] = f2b(v.w);
            *(us4*)(c1b + off) = o;
        } else if (idx < 17408) {
            size_t off = (size_t)(idx - 16384) * 4;
            float4 v = *(const float4*)(conv2_w + off);
            us4 o; o[0] = f2b(v.x); o[1] = f2b(v.y); o[2] = f2b(v.z); o[3] = f2b(v.w);
            *(us4*)(c2b + off) = o;
        }
        return;
    }
    int rg = t >> 7, cg = t & 127;
    int row0 = c * 32 + rg * 16;
    float4 s = {0.f, 0.f, 0.f, 0.f};
#pragma unroll 4
    for (int i = 0; i < 16; ++i) {
        size_t off = ((size_t)(b * NN + row0 + i) * DD) + cg * 4;
        float4 v = *(const float4*)(x + off);
        s.x += v.x; s.y += v.y; s.z += v.z; s.w += v.w;
        us4 o; o[0] = f2b(v.x); o[1] = f2b(v.y); o[2] = f2b(v.z); o[3] = f2b(v.w);
        *(us4*)(xb + off) = o;
    }
    float* pp = part + ((size_t)((b * 128 + c) * 2 + rg) * DD) + cg * 4;
    pp[0] = s.x; pp[1] = s.y; pp[2] = s.z; pp[3] = s.w;
}

// ---------------- kernel 2: gate = involution kernel weights ----------------
// grid 256 (b = bid&7, mtile = bid>>3), 256 threads / 4 waves, 128 rows per block.
// Phase 1: h = xb @ c1b^T (M=128,N=128,K=512), LDS-staged. BN+ReLU -> h_s.
// Phase 2: gate = h @ c2b^T + bias (M=128,N=32,K=128).
__global__ __launch_bounds__(256, 3) void kgate(
    const unsigned short* __restrict__ xb, const unsigned short* __restrict__ c1b,
    const float* __restrict__ bn_g, const float* __restrict__ bn_b,
    const float* __restrict__ bn_m, const float* __restrict__ bn_v,
    const unsigned short* __restrict__ c2b, const float* __restrict__ conv2_b,
    float* __restrict__ gate) {
    int bid = blockIdx.x;
    int b = bid & 7, mtile = bid >> 3;
    int row0 = mtile * 128;
    int t = threadIdx.x;
    int w = t >> 6, lane = t & 63, q = lane >> 4, l16 = lane & 15;
    int wr = (w & 1) * 64, wc = (w >> 1) * 64;

    __shared__ unsigned short As[4096], Bs[4096];   // 128x32 tiles
    __shared__ unsigned short h_s[128][136];
    __shared__ float bnS[RED], bnT[RED];

    if (t < RED) {
        float sc = bn_g[t] * rsqrtf(bn_v[t] + 1e-5f);
        bnS[t] = sc;
        bnT[t] = bn_b[t] - bn_m[t] * sc;
    }

    f4 acc[4][4];
#pragma unroll
    for (int mi = 0; mi < 4; ++mi)
#pragma unroll
        for (int ni = 0; ni < 4; ++ni) acc[mi][ni] = (f4){0.f, 0.f, 0.f, 0.f};

    const unsigned short* abase = xb + ((size_t)(b * NN + row0) * DD);
    const int r1 = t >> 2, k1 = (t & 3) * 8;            // seg t
    const int r2 = 64 + r1, k2 = k1;                    // seg t+256
    unsigned short* As1 = &As[(size_t)w * 512];         // wave-uniform lds bases
    unsigned short* As2 = &As[2048 + (size_t)w * 512];
    unsigned short* Bs1 = &Bs[(size_t)w * 512];
    unsigned short* Bs2 = &Bs[2048 + (size_t)w * 512];

    for (int ks = 0; ks < 16; ++ks) {
        __syncthreads();
        int kk = ks * 32;
        gld16(abase + (size_t)r1 * DD + kk + k1, As1);
        gld16(abase + (size_t)r2 * DD + kk + k2, As2);
        gld16(c1b + (size_t)r1 * DD + kk + k1, Bs1);
        gld16(c1b + (size_t)r2 * DD + kk + k2, Bs2);
        __syncthreads();
        bf8 af[4], bv[4];
#pragma unroll
        for (int mi = 0; mi < 4; ++mi) af[mi] = *(const bf8*)&As[(wr + mi * 16 + l16) * 32 + q * 8];
#pragma unroll
        for (int ni = 0; ni < 4; ++ni) bv[ni] = *(const bf8*)&Bs[(wc + ni * 16 + l16) * 32 + q * 8];
#pragma unroll
        for (int ni = 0; ni < 4; ++ni)
#pragma unroll
            for (int mi = 0; mi < 4; ++mi)
                acc[mi][ni] = __builtin_amdgcn_mfma_f32_16x16x32_bf16(af[mi], bv[ni], acc[mi][ni], 0, 0, 0);
    }
    __syncthreads();
    // BN + ReLU -> h_s (bf16)
#pragma unroll
    for (int ni = 0; ni < 4; ++ni) {
        int hc = wc + ni * 16 + l16;
        float sc = bnS[hc], sh = bnT[hc];
#pragma unroll
        for (int mi = 0; mi < 4; ++mi)
#pragma unroll
            for (int r = 0; r < 4; ++r) {
                int row = wr + mi * 16 + q * 4 + r;
                h_s[row][hc] = f2b(fmaxf(acc[mi][ni][r] * sc + sh, 0.f));
            }
    }
    __syncthreads();
    // Phase 2: gate = h @ c2b^T + bias. wave w: rows w*32..w*32+31, 2x2 tiles
    f4 a2[2][2];
#pragma unroll
    for (int mi = 0; mi < 2; ++mi)
#pragma unroll
        for (int ni = 0; ni < 2; ++ni) a2[mi][ni] = (f4){0.f, 0.f, 0.f, 0.f};
#pragma unroll
    for (int ks = 0; ks < 4; ++ks) {
        bf8 ah[2], bh[2];
#pragma unroll
        for (int mi = 0; mi < 2; ++mi)
            ah[mi] = *(const bf8*)&h_s[w * 32 + mi * 16 + l16][ks * 32 + q * 8];
#pragma unroll
        for (int ni = 0; ni < 2; ++ni)
            bh[ni] = *(const bf8*)(c2b + (ni * 16 + l16) * RED + ks * 32 + q * 8);
#pragma unroll
        for (int ni = 0; ni < 2; ++ni)
#pragma unroll
            for (int mi = 0; mi < 2; ++mi)
                a2[mi][ni] = __builtin_amdgcn_mfma_f32_16x16x32_bf16(ah[mi], bh[ni], a2[mi][ni], 0, 0, 0);
    }
#pragma unroll
    for (int ni = 0; ni < 2; ++ni) {
        int g = ni * 16 + l16;
        float cb = conv2_b[g];
#pragma unroll
        for (int mi = 0; mi < 2; ++mi)
#pragma unroll
            for (int r = 0; r < 4; ++r) {
                int row = w * 32 + mi * 16 + q * 4 + r;
                gate[((size_t)(b * NN + row0 + row)) * GG + g] = a2[mi][ni][r] + cb;
            }
    }
}

// ---------------- kernel 3: attention MLP + softmax + bb ----------------
__global__ __launch_bounds__(256) void katt(const float* __restrict__ part,
                                            const float* __restrict__ fc1_w,
                                            const float* __restrict__ fc2_w,
                                            const float* __restrict__ fc2_b,
                                            const float* __restrict__ dyn_b,
                                            float* __restrict__ att, float* __restrict__ bb) {
    int b = blockIdx.x, t = threadIdx.x;
    __shared__ float pooled[DD];
    __shared__ float a_s[HID + 3];
    __shared__ float att_s[4];
    {
        // each thread: cols t and t+256; ILP-4 over 256 chunks
        float s0 = 0.f, s1 = 0.f, s2 = 0.f, s3 = 0.f;
        const float* pb = part + (size_t)b * 256 * DD;
        for (int cc = 0; cc < 256; cc += 2) {
            s0 += pb[(size_t)cc * DD + t];
            s1 += pb[(size_t)cc * DD + t + 256];
            s2 += pb[(size_t)(cc + 1) * DD + t];
            s3 += pb[(size_t)(cc + 1) * DD + t + 256];
        }
        pooled[t] = (s0 + s2) * (1.0f / (float)NN);
        pooled[t + 256] = (s1 + s3) * (1.0f / (float)NN);
    }
    __syncthreads();
    int wv = t >> 6, ln = t & 63;
    for (int j = wv; j < HID; j += 4) {
        const float* wr = fc1_w + (size_t)j * DD + ln * 8;
        float4 w0 = *(const float4*)wr;
        float4 w1 = *(const float4*)(wr + 4);
        const float* pl = pooled + ln * 8;
        float s = w0.x * pl[0] + w0.y * pl[1] + w0.z * pl[2] + w0.w * pl[3] +
                  w1.x * pl[4] + w1.y * pl[5] + w1.z * pl[6] + w1.w * pl[7];
#pragma unroll
        for (int off = 32; off >= 1; off >>= 1) s += __shfl_xor(s, off);
        if (ln == 0) a_s[j] = fmaxf(s, 0.f);
    }
    __syncthreads();
    if (t == 0) {
        float lg[4], mx = -1e30f;
        for (int k = 0; k < 4; ++k) {
            float s = fc2_b[k];
            for (int j = 0; j < HID; ++j) s += a_s[j] * fc2_w[k * HID + j];
            lg[k] = s * (1.0f / 34.0f);
            mx = fmaxf(mx, lg[k]);
        }
        float den = 0.f;
        for (int k = 0; k < 4; ++k) { lg[k] = __expf(lg[k] - mx); den += lg[k]; }
        for (int k = 0; k < 4; ++k) {
            float a = lg[k] / den;
            att_s[k] = a; att[b * 4 + k] = a;
        }
    }
    __syncthreads();
    float a0 = att_s[0], a1 = att_s[1], a2 = att_s[2], a3 = att_s[3];
    for (int o = t; o < DD; o += 256) {
        bb[b * DD + o] = a0 * dyn_b[o] + a1 * dyn_b[DD + o] +
                         a2 * dyn_b[2 * DD + o] + a3 * dyn_b[3 * DD + o];
    }
}

// ---------------- kernel 4: Wb[b,o,d] = sum_k att[b,k]*dyn_w[k,o,d] ----------------
__global__ __launch_bounds__(256) void kwb(const float* __restrict__ dyn_w,
                                           const float* __restrict__ att,
                                           unsigned short* __restrict__ Wb) {
    int g = blockIdx.x * 256 + threadIdx.x;
    size_t pos = (size_t)g * 4;
    float4 w0 = *(const float4*)(dyn_w + pos);
    float4 w1 = *(const float4*)(dyn_w + 262144 + pos);
    float4 w2 = *(const float4*)(dyn_w + 524288 + pos);
    float4 w3 = *(const float4*)(dyn_w + 786432 + pos);
#pragma unroll
    for (int b = 0; b < 8; ++b) {
        float a0 = att[b * 4 + 0], a1 = att[b * 4 + 1], a2 = att[b * 4 + 2], a3 = att[b * 4 + 3];
        us4 o;
        o[0] = f2b(a0 * w0.x + a1 * w1.x + a2 * w2.x + a3 * w3.x);
        o[1] = f2b(a0 * w0.y + a1 * w1.y + a2 * w2.y + a3 * w3.y);
        o[2] = f2b(a0 * w0.z + a1 * w1.z + a2 * w2.z + a3 * w3.z);
        o[3] = f2b(a0 * w0.w + a1 * w1.w + a2 * w2.w + a3 * w3.w);
        *(us4*)(Wb + (size_t)b * 262144 + pos) = o;
    }
}

// ---------------- kernel 5: y2 = xb @ Wb^T + bb -> out (fp32, in-place staging) ----------------
// m97 structure: 128x128 tile, 256 thr / 4 waves, BK=32, global_load_lds staged.
__global__ __launch_bounds__(256, 3) void kgemm(
    const unsigned short* __restrict__ xb, const unsigned short* __restrict__ Wb,
    const float* __restrict__ bb, float* __restrict__ out) {
    int bid = blockIdx.x;
    int b = bid & 7, tile = bid >> 3;
    int ntile = tile & 3, mtile = tile >> 2;
    int row0 = mtile * 128, col0 = ntile * 128;
    int t = threadIdx.x;
    int w = t >> 6, lane = t & 63, q = lane >> 4, l16 = lane & 15;
    int wr = (w & 1) * 64, wc = (w >> 1) * 64;

    __shared__ unsigned short As[4096], Bs[4096];

    f4 acc[4][4];
#pragma unroll
    for (int mi = 0; mi < 4; ++mi)
#pragma unroll
        for (int ni = 0; ni < 4; ++ni) acc[mi][ni] = (f4){0.f, 0.f, 0.f, 0.f};

    const unsigned short* abase = xb + ((size_t)(b * NN + row0) * DD);
    const unsigned short* bbase = Wb + ((size_t)(b * DD + col0)) * DD;
    const int r1 = t >> 2, k1 = (t & 3) * 8;
    const int r2 = 64 + r1;
    unsigned short* As1 = &As[(size_t)w * 512];
    unsigned short* As2 = &As[2048 + (size_t)w * 512];
    unsigned short* Bs1 = &Bs[(size_t)w * 512];
    unsigned short* Bs2 = &Bs[2048 + (size_t)w * 512];

    for (int ks = 0; ks < 16; ++ks) {
        __syncthreads();
        int kk = ks * 32;
        gld16(abase + (size_t)r1 * DD + kk + k1, As1);
        gld16(abase + (size_t)r2 * DD + kk + k1, As2);
        gld16(bbase + (size_t)r1 * DD + kk + k1, Bs1);
        gld16(bbase + (size_t)r2 * DD + kk + k1, Bs2);
        __syncthreads();
        bf8 af[4], bv[4];
#pragma unroll
        for (int mi = 0; mi < 4; ++mi) af[mi] = *(const bf8*)&As[(wr + mi * 16 + l16) * 32 + q * 8];
#pragma unroll
        for (int ni = 0; ni < 4; ++ni) bv[ni] = *(const bf8*)&Bs[(wc + ni * 16 + l16) * 32 + q * 8];
#pragma unroll
        for (int ni = 0; ni < 4; ++ni)
#pragma unroll
            for (int mi = 0; mi < 4; ++mi)
                acc[mi][ni] = __builtin_amdgcn_mfma_f32_16x16x32_bf16(af[mi], bv[ni], acc[mi][ni], 0, 0, 0);
    }
    // epilogue: + bb, store fp32 into out (read back by kln)
    const float* bbp = bb + b * DD + col0;
#pragma unroll
    for (int ni = 0; ni < 4; ++ni) {
        int col = wc + ni * 16 + l16;
        float bbv = bbp[col];
#pragma unroll
        for (int mi = 0; mi < 4; ++mi)
#pragma unroll
            for (int r = 0; r < 4; ++r) {
                int row = wr + mi * 16 + q * 4 + r;
                out[((size_t)(b * NN + row0 + row)) * DD + col0 + col] = acc[mi][ni][r] + bbv;
            }
    }
}

// ---------------- kernel 6: y = y2 + x*gate; LayerNorm; + x; in-place on out ----------------
// 256 thr / 4 waves; one row per wave; grid 8192
__global__ __launch_bounds__(256) void kln(const unsigned short* __restrict__ xb,
                                           const float* __restrict__ gate,
                                           const float* __restrict__ lnG,
                                           const float* __restrict__ lnB,
                                           float* __restrict__ out) {
    int t = threadIdx.x;
    int w = t >> 6, lane = t & 63;
    int rid = blockIdx.x * 4 + w;              // global row 0..32767
    size_t base = (size_t)rid * DD + lane * 8;
    float4 y0 = *(const float4*)(out + base);
    float4 y1 = *(const float4*)(out + base + 4);
    us8 xv8 = *(const us8*)(xb + base);
    float g = gate[(size_t)rid * GG + (lane >> 1)];
    float xv[8], y[8];
#pragma unroll
    for (int i = 0; i < 8; ++i) xv[i] = b2f(xv8[i]);
    y[0] = y0.x + xv[0] * g; y[1] = y0.y + xv[1] * g;
    y[2] = y0.z + xv[2] * g; y[3] = y0.w + xv[3] * g;
    y[4] = y1.x + xv[4] * g; y[5] = y1.y + xv[5] * g;
    y[6] = y1.z + xv[6] * g; y[7] = y1.w + xv[7] * g;
    float s = 0.f, sq = 0.f;
#pragma unroll
    for (int i = 0; i < 8; ++i) { s += y[i]; sq += y[i] * y[i]; }
#pragma unroll
    for (int off = 32; off >= 1; off >>= 1) {
        s += __shfl_xor(s, off);
        sq += __shfl_xor(sq, off);
    }
    float mu = s * (1.f / 512.f);
    float rs = rsqrtf(sq * (1.f / 512.f) - mu * mu + 1e-5f);
    float4 g0 = *(const float4*)(lnG + lane * 8);
    float4 g1 = *(const float4*)(lnG + lane * 8 + 4);
    float4 b0 = *(const float4*)(lnB + lane * 8);
    float4 b1 = *(const float4*)(lnB + lane * 8 + 4);
    float lg[8] = {g0.x, g0.y, g0.z, g0.w, g1.x, g1.y, g1.z, g1.w};
    float lb[8] = {b0.x, b0.y, b0.z, b0.w, b1.x, b1.y, b1.z, b1.w};
    float4 o0, o1;
    o0.x = (y[0] - mu) * rs * lg[0] + lb[0] + xv[0];
    o0.y = (y[1] - mu) * rs * lg[1] + lb[1] + xv[1];
    o0.z = (y[2] - mu) * rs * lg[2] + lb[2] + xv[2];
    o0.w = (y[3] - mu) * rs * lg[3] + lb[3] + xv[3];
    o1.x = (y[4] - mu) * rs * lg[4] + lb[4] + xv[4];
    o1.y = (y[5] - mu) * rs * lg[5] + lb[5] + xv[5];
    o1.z = (y[6] - mu) * rs * lg[6] + lb[6] + xv[6];
    o1.w = (y[7] - mu) * rs * lg[7] + lb[7] + xv[7];
    *(float4*)(out + base) = o0;
    *(float4*)(out + base + 4) = o1;
}

extern "C" void kernel_launch(void* const* d_in, const int* in_sizes, int n_in,
                              void* d_out, int out_size, void* d_ws, size_t ws_size,
                              hipStream_t stream) {
    const float* x       = (const float*)d_in[0];
    const float* conv1_w = (const float*)d_in[1];
    const float* bn_g    = (const float*)d_in[2];
    const float* bn_b    = (const float*)d_in[3];
    const float* bn_m    = (const float*)d_in[4];
    const float* bn_v    = (const float*)d_in[5];
    const float* conv2_w = (const float*)d_in[6];
    const float* conv2_b = (const float*)d_in[7];
    const float* fc1_w   = (const float*)d_in[8];
    const float* fc2_w   = (const float*)d_in[9];
    const float* fc2_b   = (const float*)d_in[10];
    const float* dyn_w   = (const float*)d_in[11];
    const float* dyn_b   = (const float*)d_in[12];
    const float* lnG     = (const float*)d_in[13];
    const float* lnB     = (const float*)d_in[14];
    float* out = (float*)d_out;

    char* ws = (char*)d_ws;
    unsigned short* xb   = (unsigned short*)ws;                // 33554432
    float* part          = (float*)(ws + 33554432);            // 4194304
    float* att           = (float*)(ws + 37748736);            // 128
    float* bbw           = (float*)(ws + 37748864);            // 16384
    unsigned short* c1b  = (unsigned short*)(ws + 37765248);   // 131072
    unsigned short* c2b  = (unsigned short*)(ws + 37896320);   // 8192
    float* gate          = (float*)(ws + 37904512);            // 4194304
    unsigned short* Wb   = (unsigned short*)(ws + 42098816);   // 4194304  (total ~46.3 MB)

    kpre<<<dim3(137, 8), 256, 0, stream>>>(x, conv1_w, conv2_w, part, xb, c1b, c2b);
    kgate<<<256, 256, 0, stream>>>(xb, c1b, bn_g, bn_b, bn_m, bn_v, c2b, conv2_b, gate);
    katt<<<8, 256, 0, stream>>>(part, fc1_w, fc2_w, fc2_b, dyn_b, att, bbw);
    kwb<<<256, 256, 0, stream>>>(dyn_w, att, Wb);
    kgemm<<<1024, 256, 0, stream>>>(xb, Wb, bbw, out);
    kln<<<8192, 256, 0, stream>>>(xb, gate, lnG, lnB, out);
}